// Round 18
// baseline (79.253 us; speedup 1.0000x reference)
//
#include <hip/hip_runtime.h>
#include <hip/hip_bf16.h>

#define NN 8192
#define INC 256
#define OUTC 512
#define NE 262144
#define MAXD 128
#define JC 4
#define JLEN 128  // OUTC / JC

typedef __hip_bfloat16 bf16;
typedef short bf16x8 __attribute__((ext_vector_type(8)));
typedef float f32x16 __attribute__((ext_vector_type(16)));

__device__ inline unsigned short f2bu(float f) {
  __hip_bfloat16 b = __float2bfloat16(f);
  return *reinterpret_cast<unsigned short*>(&b);
}
__device__ inline float blo(unsigned int x) { return __uint_as_float(x << 16); }
__device__ inline float bhi(unsigned int x) { return __uint_as_float(x & 0xffff0000u); }
__device__ inline float b2f(unsigned short s) { return __uint_as_float(((unsigned int)s) << 16); }

// P0: blocks 0..511 = x col-partials (16 rows each) + bf16 cast + deg zero;
// blocks 512..1023 = Wc j-chunk partials (+ u,v partials on o-quad 0).
__global__ __launch_bounds__(256) void k_p0(const float* __restrict__ x,
                                            const float* __restrict__ W,
                                            const float* __restrict__ att_w,
                                            const float* __restrict__ lin_w,
                                            float* __restrict__ xpartT,
                                            unsigned short* __restrict__ xb,
                                            int* __restrict__ deg,
                                            float* __restrict__ part,
                                            float* __restrict__ uvpart) {
  int b = blockIdx.x, t = threadIdx.x;
  if (b < 512) {
    int gid = b * 256 + t;
    if (gid < NN) deg[gid] = 0;
    float acc = 0.f;
    int r0 = b * 16;
#pragma unroll 8
    for (int r = r0; r < r0 + 16; ++r) {
      float xv = x[r * INC + t];
      acc += xv;
      xb[r * INC + t] = f2bu(xv);
    }
    xpartT[t * 512 + b] = acc;
    return;
  }
  int bid2 = b - 512;      // 0..511
  int q = bid2 >> 2;       // o-quad 0..127
  int jc = bid2 & 3;
  int j0 = jc * JLEN;
  int o0 = q * 4;
  float a0 = 0.f, a1 = 0.f, a2 = 0.f, a3 = 0.f, su = 0.f, sv = 0.f;
  const float* lw0 = lin_w + (size_t)(o0 + 0) * OUTC + j0;
  const float* lw1 = lin_w + (size_t)(o0 + 1) * OUTC + j0;
  const float* lw2 = lin_w + (size_t)(o0 + 2) * OUTC + j0;
  const float* lw3 = lin_w + (size_t)(o0 + 3) * OUTC + j0;
#pragma unroll 8
  for (int jj = 0; jj < JLEN; ++jj) {
    float wv = W[(j0 + jj) * INC + t];
    a0 = fmaf(lw0[jj], wv, a0);
    a1 = fmaf(lw1[jj], wv, a1);
    a2 = fmaf(lw2[jj], wv, a2);
    a3 = fmaf(lw3[jj], wv, a3);
    if (q == 0) { su = fmaf(att_w[j0 + jj], wv, su); sv += wv; }
  }
  float* pb = part + ((size_t)jc * OUTC + o0) * INC + t;
  pb[0] = a0;
  pb[INC] = a1;
  pb[2 * INC] = a2;
  pb[3 * INC] = a3;
  if (q == 0) {
    uvpart[(jc * 2 + 0) * INC + t] = su;
    uvpart[(jc * 2 + 1) * INC + t] = sv;
  }
}

// P1 (385 blocks):
//  blocks 0..255: xsum reduce (512 partials) + 4 edges/thread atomic scatter
//  blocks 256..383: Wc reduce -> Wcb bf16
//  block 384: u,v
__global__ __launch_bounds__(256) void k_p1(const float* __restrict__ xpartT,
                                            float* __restrict__ xsum,
                                            const int* __restrict__ erow,
                                            const int* __restrict__ ecol,
                                            int* __restrict__ deg,
                                            int* __restrict__ colbuf2,
                                            const float* __restrict__ part,
                                            const float* __restrict__ uvpart,
                                            unsigned short* __restrict__ Wcb,
                                            float* __restrict__ u,
                                            float* __restrict__ v) {
  __shared__ float sred[4];
  int b = blockIdx.x, t = threadIdx.x;
  int l = t & 63, w = t >> 6;
  if (b < 256) {
    float r = xpartT[b * 512 + t] + xpartT[b * 512 + t + 256];
#pragma unroll
    for (int off = 32; off > 0; off >>= 1) r += __shfl_xor(r, off);
    if (l == 0) sred[w] = r;
    int e0 = (b * 256 + t) * 4;
    int4 ev = *(const int4*)(erow + e0);
    int4 ec = *(const int4*)(ecol + e0);
    int s0 = atomicAdd(&deg[ev.x], 1);
    if (s0 < MAXD) colbuf2[ev.x * MAXD + s0] = ec.x;
    int s1 = atomicAdd(&deg[ev.y], 1);
    if (s1 < MAXD) colbuf2[ev.y * MAXD + s1] = ec.y;
    int s2 = atomicAdd(&deg[ev.z], 1);
    if (s2 < MAXD) colbuf2[ev.z * MAXD + s2] = ec.z;
    int s3 = atomicAdd(&deg[ev.w], 1);
    if (s3 < MAXD) colbuf2[ev.w * MAXD + s3] = ec.w;
    __syncthreads();
    if (t == 0) xsum[b] = sred[0] + sred[1] + sred[2] + sred[3];
  } else if (b < 384) {
    int o0 = (b - 256) * 4;
#pragma unroll
    for (int oo = 0; oo < 4; ++oo) {
      float s = 0.f;
#pragma unroll
      for (int jc = 0; jc < JC; ++jc)
        s += part[((size_t)jc * OUTC + o0 + oo) * INC + t];
      Wcb[(size_t)(o0 + oo) * INC + t] = f2bu(s);
    }
  } else {
    float su = 0.f, sv = 0.f;
#pragma unroll
    for (int jc = 0; jc < JC; ++jc) {
      su += uvpart[(jc * 2 + 0) * INC + t];
      sv += uvpart[(jc * 2 + 1) * INC + t];
    }
    u[t] = su;
    v[t] = sv;
  }
}

// Coeff + gather-x aggregation: one wave per row.
// y[i,:] = sum_k cf_k * xb[col_k, :]  (bf16 out), rowscale[i] = e^{-M}/Z.
// Blocks 2048..2079: gsum[o] = Wcb[o,:].xsum
__global__ __launch_bounds__(256) void k_sagg2(const float* __restrict__ x,
                                               const float* __restrict__ u,
                                               const float* __restrict__ v,
                                               const unsigned short* __restrict__ xb,
                                               const int* __restrict__ deg,
                                               const int* __restrict__ colbuf2,
                                               const unsigned short* __restrict__ Wcb,
                                               const float* __restrict__ xsum,
                                               unsigned short* __restrict__ y,
                                               float* __restrict__ rowscale,
                                               float* __restrict__ gsum) {
  int bk = blockIdx.x, t = threadIdx.x;
  int w = t >> 6, l = t & 63;
  if (bk >= 2048) {
    __shared__ float sredg[4];
    int o0 = (bk - 2048) * 16;
    float xk = xsum[t];
    for (int oo = 0; oo < 16; ++oo) {
      float r = b2f(Wcb[(size_t)(o0 + oo) * INC + t]) * xk;
#pragma unroll
      for (int off = 32; off > 0; off >>= 1) r += __shfl_xor(r, off);
      if (l == 0) sredg[w] = r;
      __syncthreads();
      if (t == 0) gsum[o0 + oo] = sredg[0] + sredg[1] + sredg[2] + sredg[3];
      __syncthreads();
    }
    return;
  }
  __shared__ int scols[4][MAXD];
  __shared__ float scoef[4][MAXD];
  int i = bk * 4 + w;

  // alpha_i = leaky_relu((x_i.u)*(x_i.v))
  float su = 0.f, sv = 0.f;
#pragma unroll
  for (int kk = 0; kk < 4; ++kk) {
    int k = l + kk * 64;
    float xv = x[(size_t)i * INC + k];
    su = fmaf(xv, u[k], su);
    sv = fmaf(xv, v[k], sv);
  }
#pragma unroll
  for (int off = 32; off > 0; off >>= 1) {
    su += __shfl_xor(su, off);
    sv += __shfl_xor(sv, off);
  }
  float a = su * sv;
  float al = a > 0.f ? a : 0.2f * a;

  int d = deg[i];
  if (d > MAXD) d = MAXD;
  const int* crow = colbuf2 + (size_t)i * MAXD;
  if (l < d) scols[w][l] = crow[l];
  int l2 = l + 64;
  if (l2 < d) scols[w][l2] = crow[l2];
  __syncthreads();
  int c0s = -1, c1s = -2;
  if (l < d) c0s = scols[w][l];
  if (l2 < d) c1s = scols[w][l2];
  int m0 = 0, m1 = 0, f0 = 1, f1 = 1;
  for (int q = 0; q < d; ++q) {
    int cq = scols[w][q];
    if (cq == c0s) { m0++; if (q < l) f0 = 0; }
    if (cq == c1s) { m1++; if (q < l2) f1 = 0; }
  }
  int mm = m0 > m1 ? m0 : m1;
#pragma unroll
  for (int off = 32; off > 0; off >>= 1) {
    int b = __shfl_xor(mm, off);
    if (b > mm) mm = b;
  }
  float M = (al > 0.f) ? al * (float)mm : 0.f;
  float eMn = expf(-M);
  float se = 0.f;
  int nc = 0;
  float cf0 = 0.f, cf1 = 0.f;
  if (l < d && f0) {
    float e0 = expf(al * (float)m0 - M);
    se += e0; nc++; cf0 = e0 - eMn;
  }
  if (l2 < d && f1) {
    float e1 = expf(al * (float)m1 - M);
    se += e1; nc++; cf1 = e1 - eMn;
  }
#pragma unroll
  for (int off = 32; off > 0; off >>= 1) {
    se += __shfl_xor(se, off);
    nc += __shfl_xor(nc, off);
  }
  float Z = (float)(NN - nc) * eMn + se;
  float invZ = 1.0f / Z;
  if (l < d) scoef[w][l] = cf0 * invZ;
  if (l2 < d) scoef[w][l2] = cf1 * invZ;
  if (l == 0) rowscale[i] = eMn * invZ;

  // gather x rows: lane owns channels [4l, 4l+4); 4-way unrolled (4 loads in flight).
  int c0 = l * 4;
  float acc0 = 0.f, acc1 = 0.f, acc2 = 0.f, acc3 = 0.f;
  int k = 0;
  for (; k + 4 <= d; k += 4) {
    int ca = scols[w][k], cb = scols[w][k + 1];
    int cc = scols[w][k + 2], cd = scols[w][k + 3];
    float fa = scoef[w][k], fb = scoef[w][k + 1];
    float fc = scoef[w][k + 2], fd = scoef[w][k + 3];
    uint2 pa = *(const uint2*)(xb + (size_t)ca * INC + c0);
    uint2 pb = *(const uint2*)(xb + (size_t)cb * INC + c0);
    uint2 pc = *(const uint2*)(xb + (size_t)cc * INC + c0);
    uint2 pd = *(const uint2*)(xb + (size_t)cd * INC + c0);
    acc0 = fmaf(fa, blo(pa.x), fmaf(fb, blo(pb.x), acc0));
    acc1 = fmaf(fa, bhi(pa.x), fmaf(fb, bhi(pb.x), acc1));
    acc2 = fmaf(fa, blo(pa.y), fmaf(fb, blo(pb.y), acc2));
    acc3 = fmaf(fa, bhi(pa.y), fmaf(fb, bhi(pb.y), acc3));
    acc0 = fmaf(fc, blo(pc.x), fmaf(fd, blo(pd.x), acc0));
    acc1 = fmaf(fc, bhi(pc.x), fmaf(fd, bhi(pd.x), acc1));
    acc2 = fmaf(fc, blo(pc.y), fmaf(fd, blo(pd.y), acc2));
    acc3 = fmaf(fc, bhi(pc.y), fmaf(fd, bhi(pd.y), acc3));
  }
  for (; k < d; ++k) {
    int ca = scols[w][k];
    float fa = scoef[w][k];
    uint2 pa = *(const uint2*)(xb + (size_t)ca * INC + c0);
    acc0 = fmaf(fa, blo(pa.x), acc0);
    acc1 = fmaf(fa, bhi(pa.x), acc1);
    acc2 = fmaf(fa, blo(pa.y), acc2);
    acc3 = fmaf(fa, bhi(pa.y), acc3);
  }
  ushort4 yo;
  yo.x = f2bu(acc0);
  yo.y = f2bu(acc1);
  yo.z = f2bu(acc2);
  yo.w = f2bu(acc3);
  *(ushort4*)(y + (size_t)i * INC + c0) = yo;
}

// out = elu( y @ Wcb^T + rowscale*gsum )  [8192,512] f32, written directly.
// MFMA 32x32x16, 64x64 tile, 2x2 waves; fused epilogue.
__global__ __launch_bounds__(256) void k_gemm4(const unsigned short* __restrict__ y,
                                               const unsigned short* __restrict__ wb,
                                               const float* __restrict__ rowscale,
                                               const float* __restrict__ gsum,
                                               float* __restrict__ out) {
  __shared__ float srs[64];
  int bk = blockIdx.x, t = threadIdx.x;
  int w = t >> 6, l = t & 63;
  int bx = bk & 7, by = bk >> 3;
  if (t < 64) srs[t] = rowscale[by * 64 + t];
  int wm = w >> 1, wn = w & 1;
  int r0 = by * 64 + wm * 32;
  int c0 = bx * 64 + wn * 32;
  int lr = l & 31;
  int lk = (l >> 5) * 8;
  const unsigned short* pa = y + (size_t)(r0 + lr) * INC + lk;
  const unsigned short* pb = wb + (size_t)(c0 + lr) * INC + lk;
  f32x16 acc = {};
#pragma unroll
  for (int k0 = 0; k0 < INC; k0 += 16) {
    bf16x8 a = *(const bf16x8*)(pa + k0);
    bf16x8 b = *(const bf16x8*)(pb + k0);
    acc = __builtin_amdgcn_mfma_f32_32x32x16_bf16(a, b, acc, 0, 0, 0);
  }
  __syncthreads();
  // C/D: col = lane&31, row = (reg&3) + 8*(reg>>2) + 4*(lane>>5)
  int col = c0 + lr;
  float gs = gsum[col];
  int lrb = wm * 32 + 4 * (l >> 5);
#pragma unroll
  for (int reg = 0; reg < 16; ++reg) {
    int lrow = lrb + (reg & 3) + 8 * (reg >> 2);
    float val = acc[reg] + srs[lrow] * gs;
    val = val > 0.f ? val : expm1f(val);
    out[(size_t)(by * 64 + lrow) * OUTC + col] = val;
  }
}

extern "C" void kernel_launch(void* const* d_in, const int* in_sizes, int n_in,
                              void* d_out, int out_size, void* d_ws, size_t ws_size,
                              hipStream_t stream) {
  const float* x = (const float*)d_in[0];
  const int* ei = (const int*)d_in[1];
  const float* W = (const float*)d_in[2];
  const float* att_w = (const float*)d_in[3];
  const float* lin_w = (const float*)d_in[4];
  float* out = (float*)d_out;
  const int* erow = ei;
  const int* ecol = ei + NE;

  char* ws = (char*)d_ws;
  size_t off = 0;
  auto alloc = [&](size_t bytes) {
    void* p = ws + off;
    off = (off + bytes + 255) & ~(size_t)255;
    return p;
  };
  float* u = (float*)alloc(INC * 4);
  float* v = (float*)alloc(INC * 4);
  float* xsum = (float*)alloc(INC * 4);
  float* xpartT = (float*)alloc((size_t)INC * 512 * 4);
  float* gsum = (float*)alloc(OUTC * 4);
  float* rowscale = (float*)alloc(NN * 4);
  float* part = (float*)alloc((size_t)JC * OUTC * INC * 4);
  float* uvpart = (float*)alloc(JC * 2 * INC * 4);
  unsigned short* Wcb = (unsigned short*)alloc((size_t)OUTC * INC * 2);
  unsigned short* xb = (unsigned short*)alloc((size_t)NN * INC * 2);
  unsigned short* y = (unsigned short*)alloc((size_t)NN * INC * 2);
  int* deg = (int*)alloc(NN * 4);
  int* colbuf2 = (int*)alloc((size_t)NN * MAXD * 4);
  (void)ws_size; (void)in_sizes; (void)n_in; (void)out_size;

  k_p0<<<512 + 512, 256, 0, stream>>>(x, W, att_w, lin_w, xpartT, xb, deg, part, uvpart);
  k_p1<<<385, 256, 0, stream>>>(xpartT, xsum, erow, ecol, deg, colbuf2, part, uvpart, Wcb, u, v);
  k_sagg2<<<NN / 4 + 32, 256, 0, stream>>>(x, u, v, xb, deg, colbuf2, Wcb, xsum, y, rowscale, gsum);
  k_gemm4<<<1024, 256, 0, stream>>>(y, Wcb, rowscale, gsum, out);
}

// Round 19
// 70.629 us; speedup vs baseline: 1.1221x; 1.1221x over previous
//
#include <hip/hip_runtime.h>
#include <hip/hip_bf16.h>

#define NN 8192
#define INC 256
#define OUTC 512
#define NE 262144
#define MAXD 128
#define JC 8
#define JLEN 64  // OUTC / JC

typedef __hip_bfloat16 bf16;
typedef short bf16x8 __attribute__((ext_vector_type(8)));
typedef float f32x16 __attribute__((ext_vector_type(16)));

__device__ inline unsigned short f2bu(float f) {
  __hip_bfloat16 b = __float2bfloat16(f);
  return *reinterpret_cast<unsigned short*>(&b);
}
__device__ inline float blo(unsigned int x) { return __uint_as_float(x << 16); }
__device__ inline float bhi(unsigned int x) { return __uint_as_float(x & 0xffff0000u); }
__device__ inline float b2f(unsigned short s) { return __uint_as_float(((unsigned int)s) << 16); }

// P0: blocks 0..255 = x col-partials + bf16 cast + deg zero;
// blocks 256..1279 = Wc j-chunk partials (+ u,v partials on o-quad 0).
__global__ __launch_bounds__(256) void k_p0(const float* __restrict__ x,
                                            const float* __restrict__ W,
                                            const float* __restrict__ att_w,
                                            const float* __restrict__ lin_w,
                                            float* __restrict__ xpartT,
                                            unsigned short* __restrict__ xb,
                                            int* __restrict__ deg,
                                            float* __restrict__ part,
                                            float* __restrict__ uvpart) {
  int b = blockIdx.x, t = threadIdx.x;
  if (b < 256) {
    int gid = b * 256 + t;
    if (gid < NN) deg[gid] = 0;
    float acc = 0.f;
    int r0 = b * (NN / 256);
#pragma unroll 8
    for (int r = r0; r < r0 + NN / 256; ++r) {
      float xv = x[r * INC + t];
      acc += xv;
      xb[r * INC + t] = f2bu(xv);
    }
    xpartT[t * 256 + b] = acc;
    return;
  }
  int bid2 = b - 256;      // 0..1023
  int q = bid2 >> 3;       // o-quad 0..127
  int jc = bid2 & 7;
  int j0 = jc * JLEN;
  int o0 = q * 4;
  float a0 = 0.f, a1 = 0.f, a2 = 0.f, a3 = 0.f, su = 0.f, sv = 0.f;
  const float* lw0 = lin_w + (size_t)(o0 + 0) * OUTC + j0;
  const float* lw1 = lin_w + (size_t)(o0 + 1) * OUTC + j0;
  const float* lw2 = lin_w + (size_t)(o0 + 2) * OUTC + j0;
  const float* lw3 = lin_w + (size_t)(o0 + 3) * OUTC + j0;
#pragma unroll 8
  for (int jj = 0; jj < JLEN; ++jj) {
    float wv = W[(j0 + jj) * INC + t];
    a0 = fmaf(lw0[jj], wv, a0);
    a1 = fmaf(lw1[jj], wv, a1);
    a2 = fmaf(lw2[jj], wv, a2);
    a3 = fmaf(lw3[jj], wv, a3);
    if (q == 0) { su = fmaf(att_w[j0 + jj], wv, su); sv += wv; }
  }
  float* pb = part + ((size_t)jc * OUTC + o0) * INC + t;
  pb[0] = a0;
  pb[INC] = a1;
  pb[2 * INC] = a2;
  pb[3 * INC] = a3;
  if (q == 0) {
    uvpart[(jc * 2 + 0) * INC + t] = su;
    uvpart[(jc * 2 + 1) * INC + t] = sv;
  }
}

// P1 (385 blocks):
//  blocks 0..255: xsum reduce + 4 edges/thread atomicAdd(deg)->slot scatter
//  blocks 256..383: Wc reduce -> Wcb bf16
//  block 384: u,v
__global__ __launch_bounds__(256) void k_p1(const float* __restrict__ xpartT,
                                            float* __restrict__ xsum,
                                            const int* __restrict__ erow,
                                            const int* __restrict__ ecol,
                                            int* __restrict__ deg,
                                            int* __restrict__ colbuf2,
                                            const float* __restrict__ part,
                                            const float* __restrict__ uvpart,
                                            unsigned short* __restrict__ Wcb,
                                            float* __restrict__ u,
                                            float* __restrict__ v) {
  __shared__ float sred[4];
  int b = blockIdx.x, t = threadIdx.x;
  int l = t & 63, w = t >> 6;
  if (b < 256) {
    float r = xpartT[b * 256 + t];
#pragma unroll
    for (int off = 32; off > 0; off >>= 1) r += __shfl_xor(r, off);
    if (l == 0) sred[w] = r;
    int e0 = (b * 256 + t) * 4;
    int4 ev = *(const int4*)(erow + e0);
    int4 ec = *(const int4*)(ecol + e0);
    int s0 = atomicAdd(&deg[ev.x], 1);
    if (s0 < MAXD) colbuf2[ev.x * MAXD + s0] = ec.x;
    int s1 = atomicAdd(&deg[ev.y], 1);
    if (s1 < MAXD) colbuf2[ev.y * MAXD + s1] = ec.y;
    int s2 = atomicAdd(&deg[ev.z], 1);
    if (s2 < MAXD) colbuf2[ev.z * MAXD + s2] = ec.z;
    int s3 = atomicAdd(&deg[ev.w], 1);
    if (s3 < MAXD) colbuf2[ev.w * MAXD + s3] = ec.w;
    __syncthreads();
    if (t == 0) xsum[b] = sred[0] + sred[1] + sred[2] + sred[3];
  } else if (b < 384) {
    int o0 = (b - 256) * 4;
#pragma unroll
    for (int oo = 0; oo < 4; ++oo) {
      float s = 0.f;
#pragma unroll
      for (int jc = 0; jc < JC; ++jc)
        s += part[((size_t)jc * OUTC + o0 + oo) * INC + t];
      Wcb[(size_t)(o0 + oo) * INC + t] = f2bu(s);
    }
  } else {
    float su = 0.f, sv = 0.f;
#pragma unroll
    for (int jc = 0; jc < JC; ++jc) {
      su += uvpart[(jc * 2 + 0) * INC + t];
      sv += uvpart[(jc * 2 + 1) * INC + t];
    }
    u[t] = su;
    v[t] = sv;
  }
}

// Coeff + gather-x aggregation: one wave per row.
// y[i,:] = sum_k cf_k * xb[col_k, :]  (bf16 out), rowscale[i] = e^{-M}/Z.
// Blocks 2048..2079: gsum[o] = Wcb[o,:].xsum
__global__ __launch_bounds__(256) void k_sagg2(const float* __restrict__ x,
                                               const float* __restrict__ u,
                                               const float* __restrict__ v,
                                               const unsigned short* __restrict__ xb,
                                               const int* __restrict__ deg,
                                               const int* __restrict__ colbuf2,
                                               const unsigned short* __restrict__ Wcb,
                                               const float* __restrict__ xsum,
                                               unsigned short* __restrict__ y,
                                               float* __restrict__ rowscale,
                                               float* __restrict__ gsum) {
  int bk = blockIdx.x, t = threadIdx.x;
  int w = t >> 6, l = t & 63;
  if (bk >= 2048) {
    __shared__ float sredg[4];
    int o0 = (bk - 2048) * 16;
    float xk = xsum[t];
    for (int oo = 0; oo < 16; ++oo) {
      float r = b2f(Wcb[(size_t)(o0 + oo) * INC + t]) * xk;
#pragma unroll
      for (int off = 32; off > 0; off >>= 1) r += __shfl_xor(r, off);
      if (l == 0) sredg[w] = r;
      __syncthreads();
      if (t == 0) gsum[o0 + oo] = sredg[0] + sredg[1] + sredg[2] + sredg[3];
      __syncthreads();
    }
    return;
  }
  __shared__ int scols[4][MAXD];
  __shared__ float scoef[4][MAXD];
  int i = bk * 4 + w;

  // alpha_i = leaky_relu((x_i.u)*(x_i.v))
  float su = 0.f, sv = 0.f;
#pragma unroll
  for (int kk = 0; kk < 4; ++kk) {
    int k = l + kk * 64;
    float xv = x[(size_t)i * INC + k];
    su = fmaf(xv, u[k], su);
    sv = fmaf(xv, v[k], sv);
  }
#pragma unroll
  for (int off = 32; off > 0; off >>= 1) {
    su += __shfl_xor(su, off);
    sv += __shfl_xor(sv, off);
  }
  float a = su * sv;
  float al = a > 0.f ? a : 0.2f * a;

  int d = deg[i];
  if (d > MAXD) d = MAXD;
  const int* crow = colbuf2 + (size_t)i * MAXD;
  if (l < d) scols[w][l] = crow[l];
  int l2 = l + 64;
  if (l2 < d) scols[w][l2] = crow[l2];
  __syncthreads();
  int c0s = -1, c1s = -2;
  if (l < d) c0s = scols[w][l];
  if (l2 < d) c1s = scols[w][l2];
  int m0 = 0, m1 = 0, f0 = 1, f1 = 1;
  for (int q = 0; q < d; ++q) {
    int cq = scols[w][q];
    if (cq == c0s) { m0++; if (q < l) f0 = 0; }
    if (cq == c1s) { m1++; if (q < l2) f1 = 0; }
  }
  int mm = m0 > m1 ? m0 : m1;
#pragma unroll
  for (int off = 32; off > 0; off >>= 1) {
    int b = __shfl_xor(mm, off);
    if (b > mm) mm = b;
  }
  float M = (al > 0.f) ? al * (float)mm : 0.f;
  float eMn = expf(-M);
  float se = 0.f;
  int nc = 0;
  float cf0 = 0.f, cf1 = 0.f;
  if (l < d && f0) {
    float e0 = expf(al * (float)m0 - M);
    se += e0; nc++; cf0 = e0 - eMn;
  }
  if (l2 < d && f1) {
    float e1 = expf(al * (float)m1 - M);
    se += e1; nc++; cf1 = e1 - eMn;
  }
#pragma unroll
  for (int off = 32; off > 0; off >>= 1) {
    se += __shfl_xor(se, off);
    nc += __shfl_xor(nc, off);
  }
  float Z = (float)(NN - nc) * eMn + se;
  float invZ = 1.0f / Z;
  if (l < d) scoef[w][l] = cf0 * invZ;
  if (l2 < d) scoef[w][l2] = cf1 * invZ;
  if (l == 0) rowscale[i] = eMn * invZ;

  // gather x rows: lane owns channels [4l, 4l+4); 4-way unrolled (4 loads in flight).
  int c0 = l * 4;
  float acc0 = 0.f, acc1 = 0.f, acc2 = 0.f, acc3 = 0.f;
  int k = 0;
  for (; k + 4 <= d; k += 4) {
    int ca = scols[w][k], cb = scols[w][k + 1];
    int cc = scols[w][k + 2], cd = scols[w][k + 3];
    float fa = scoef[w][k], fb = scoef[w][k + 1];
    float fc = scoef[w][k + 2], fd = scoef[w][k + 3];
    uint2 pa = *(const uint2*)(xb + (size_t)ca * INC + c0);
    uint2 pb = *(const uint2*)(xb + (size_t)cb * INC + c0);
    uint2 pc = *(const uint2*)(xb + (size_t)cc * INC + c0);
    uint2 pd = *(const uint2*)(xb + (size_t)cd * INC + c0);
    acc0 = fmaf(fa, blo(pa.x), fmaf(fb, blo(pb.x), acc0));
    acc1 = fmaf(fa, bhi(pa.x), fmaf(fb, bhi(pb.x), acc1));
    acc2 = fmaf(fa, blo(pa.y), fmaf(fb, blo(pb.y), acc2));
    acc3 = fmaf(fa, bhi(pa.y), fmaf(fb, bhi(pb.y), acc3));
    acc0 = fmaf(fc, blo(pc.x), fmaf(fd, blo(pd.x), acc0));
    acc1 = fmaf(fc, bhi(pc.x), fmaf(fd, bhi(pd.x), acc1));
    acc2 = fmaf(fc, blo(pc.y), fmaf(fd, blo(pd.y), acc2));
    acc3 = fmaf(fc, bhi(pc.y), fmaf(fd, bhi(pd.y), acc3));
  }
  for (; k < d; ++k) {
    int ca = scols[w][k];
    float fa = scoef[w][k];
    uint2 pa = *(const uint2*)(xb + (size_t)ca * INC + c0);
    acc0 = fmaf(fa, blo(pa.x), acc0);
    acc1 = fmaf(fa, bhi(pa.x), acc1);
    acc2 = fmaf(fa, blo(pa.y), acc2);
    acc3 = fmaf(fa, bhi(pa.y), acc3);
  }
  ushort4 yo;
  yo.x = f2bu(acc0);
  yo.y = f2bu(acc1);
  yo.z = f2bu(acc2);
  yo.w = f2bu(acc3);
  *(ushort4*)(y + (size_t)i * INC + c0) = yo;
}

// out = elu( y @ Wcb^T + rowscale*gsum )  [8192,512] f32, written directly.
// MFMA 32x32x16, 64x64 tile, 2x2 waves; fused epilogue.
__global__ __launch_bounds__(256) void k_gemm4(const unsigned short* __restrict__ y,
                                               const unsigned short* __restrict__ wb,
                                               const float* __restrict__ rowscale,
                                               const float* __restrict__ gsum,
                                               float* __restrict__ out) {
  __shared__ float srs[64];
  int bk = blockIdx.x, t = threadIdx.x;
  int w = t >> 6, l = t & 63;
  int bx = bk & 7, by = bk >> 3;
  if (t < 64) srs[t] = rowscale[by * 64 + t];
  int wm = w >> 1, wn = w & 1;
  int r0 = by * 64 + wm * 32;
  int c0 = bx * 64 + wn * 32;
  int lr = l & 31;
  int lk = (l >> 5) * 8;
  const unsigned short* pa = y + (size_t)(r0 + lr) * INC + lk;
  const unsigned short* pb = wb + (size_t)(c0 + lr) * INC + lk;
  f32x16 acc = {};
#pragma unroll
  for (int k0 = 0; k0 < INC; k0 += 16) {
    bf16x8 a = *(const bf16x8*)(pa + k0);
    bf16x8 b = *(const bf16x8*)(pb + k0);
    acc = __builtin_amdgcn_mfma_f32_32x32x16_bf16(a, b, acc, 0, 0, 0);
  }
  __syncthreads();
  // C/D: col = lane&31, row = (reg&3) + 8*(reg>>2) + 4*(lane>>5)
  int col = c0 + lr;
  float gs = gsum[col];
  int lrb = wm * 32 + 4 * (l >> 5);
#pragma unroll
  for (int reg = 0; reg < 16; ++reg) {
    int lrow = lrb + (reg & 3) + 8 * (reg >> 2);
    float val = acc[reg] + srs[lrow] * gs;
    val = val > 0.f ? val : expm1f(val);
    out[(size_t)(by * 64 + lrow) * OUTC + col] = val;
  }
}

extern "C" void kernel_launch(void* const* d_in, const int* in_sizes, int n_in,
                              void* d_out, int out_size, void* d_ws, size_t ws_size,
                              hipStream_t stream) {
  const float* x = (const float*)d_in[0];
  const int* ei = (const int*)d_in[1];
  const float* W = (const float*)d_in[2];
  const float* att_w = (const float*)d_in[3];
  const float* lin_w = (const float*)d_in[4];
  float* out = (float*)d_out;
  const int* erow = ei;
  const int* ecol = ei + NE;

  char* ws = (char*)d_ws;
  size_t off = 0;
  auto alloc = [&](size_t bytes) {
    void* p = ws + off;
    off = (off + bytes + 255) & ~(size_t)255;
    return p;
  };
  float* u = (float*)alloc(INC * 4);
  float* v = (float*)alloc(INC * 4);
  float* xsum = (float*)alloc(INC * 4);
  float* xpartT = (float*)alloc(INC * 256 * 4);
  float* gsum = (float*)alloc(OUTC * 4);
  float* rowscale = (float*)alloc(NN * 4);
  float* part = (float*)alloc((size_t)JC * OUTC * INC * 4);
  float* uvpart = (float*)alloc(JC * 2 * INC * 4);
  unsigned short* Wcb = (unsigned short*)alloc((size_t)OUTC * INC * 2);
  unsigned short* xb = (unsigned short*)alloc((size_t)NN * INC * 2);
  unsigned short* y = (unsigned short*)alloc((size_t)NN * INC * 2);
  int* deg = (int*)alloc(NN * 4);
  int* colbuf2 = (int*)alloc((size_t)NN * MAXD * 4);
  (void)ws_size; (void)in_sizes; (void)n_in; (void)out_size;

  k_p0<<<256 + 1024, 256, 0, stream>>>(x, W, att_w, lin_w, xpartT, xb, deg, part, uvpart);
  k_p1<<<385, 256, 0, stream>>>(xpartT, xsum, erow, ecol, deg, colbuf2, part, uvpart, Wcb, u, v);
  k_sagg2<<<NN / 4 + 32, 256, 0, stream>>>(x, u, v, xb, deg, colbuf2, Wcb, xsum, y, rowscale, gsum);
  k_gemm4<<<1024, 256, 0, stream>>>(y, Wcb, rowscale, gsum, out);
}